// Round 5
// baseline (266.754 us; speedup 1.0000x reference)
//
#include <hip/hip_runtime.h>

#define NQ     14
#define NL     4
#define BATCH  2048
#define DIM    16384
#define BLK    512

using f2 = __attribute__((ext_vector_type(2))) float;

__device__ __forceinline__ f2 swapf2(f2 v) { return __builtin_shufflevector(v, v, 1, 0); }

// RX on register-index bit B of a 32-amp (f2) tile, packed-FP32 form.
template <int B>
__device__ __forceinline__ void rot_bit(f2* v, float c, float s) {
  const f2 C = {c, c};
  const f2 S = {s, -s};
#pragma unroll
  for (int j = 0; j < 32; ++j) {
    if (!(j & B)) {
      const int j1 = j | B;
      const f2 a0 = v[j], a1 = v[j1];
      v[j]  = __builtin_elementwise_fma(C, a0, S * swapf2(a1));
      v[j1] = __builtin_elementwise_fma(C, a1, S * swapf2(a0));
    }
  }
}

// CNOT-ring basis map (linear over GF(2)): jf(k) = (y & 0x1FFF) | ((y0^k13)<<13), y=suffix-xor(k)
__device__ __forceinline__ int cnot_map(int k) {
  int y = k; y ^= y >> 1; y ^= y >> 2; y ^= y >> 4; y ^= y >> 8;
  return (y & 0x1FFF) | (((y ^ (k >> 13)) & 1) << 13);
}
// compile-time images of amp-bits 9..13 under the CNOT map
__host__ __device__ constexpr int G_of(int j) {
  int g = 0;
  if (j & 1)  g ^= 0x23FF;  // M(e9)
  if (j & 2)  g ^= 0x27FF;  // M(e10)
  if (j & 4)  g ^= 0x2FFF;  // M(e11)
  if (j & 8)  g ^= 0x3FFF;  // M(e12)
  if (j & 16) g ^= 0x1FFF;  // M(e13)
  return g;
}

__global__ __launch_bounds__(BLK, 2) void qsim_kernel(const float* __restrict__ x,
                                                      const float* __restrict__ params,
                                                      float* __restrict__ out) {
  // fixed layout: logical chunk c (amps 2c,2c+1) at physical chunk c + (c>>4)
  __shared__ float4 lds4[DIM / 2 + DIM / 32];  // 8704 chunks = 139264 B
  __shared__ float exc[NQ], exs[NQ];
  __shared__ float gc[NL * NQ], gs[NL * NQ];
  __shared__ float red[8][NQ];
  f2* lds2 = reinterpret_cast<f2*>(lds4);      // f2 slot s -> phys s + 2*(s>>5)

  const int b = blockIdx.x;
  const int t = threadIdx.x;

  if (t < NQ)      { const float xv = x[b * NQ + t]; exc[t] = cosf(0.5f * xv); exs[t] = sinf(0.5f * xv); }
  if (t < NL * NQ) { const float th = 0.5f * params[t]; gc[t] = cosf(th); gs[t] = sinf(th); }
  __syncthreads();

  float4 tile[16];
  f2* v = reinterpret_cast<f2*>(tile);

  // ---- embedding in pass-A ownership: amp a = (t<<5)|j ; a-bit p <-> qubit 13-p
  {
    float pb = 1.0f;
#pragma unroll
    for (int pt = 0; pt < 9; ++pt) pb *= ((t >> pt) & 1) ? exs[8 - pt] : exc[8 - pt];
    const int pct = __popc(t);
#pragma unroll
    for (int j = 0; j < 32; ++j) {
      float f = pb;
#pragma unroll
      for (int bb = 0; bb < 5; ++bb) f *= ((j >> bb) & 1) ? exs[13 - bb] : exc[13 - bb];
      const int pc = (pct + __popc(j)) & 3;
      f2 av;
      av.x = (pc == 0) ? f : ((pc == 2) ? -f : 0.0f);
      av.y = (pc == 1) ? -f : ((pc == 3) ? f : 0.0f);
      v[j] = av;
    }
  }

  const int baseA = 17 * t;                 // phys chunk of c=16t (pass A, self-owned)
  const int baseB = (t & 15) + 272 * (t >> 4); // phys chunk; offsets 17*jj (intra-wave group t>>4)
  const int baseC = t + 2 * (t >> 5);       // phys f2 slot; offsets 544*j
  const int jft   = cnot_map(t);

  // CNOT scatter byte-offsets are layer-invariant: precompute once
  int soff[32];
#pragma unroll
  for (int j = 0; j < 32; ++j) {
    const int s = jft ^ G_of(j);
    soff[j] = (s + 2 * (s >> 5)) * 8;       // pad-swizzled f2 slot, in bytes
  }
  char* const sbase = (char*)lds2;

  for (int layer = 0; layer < NL; ++layer) {  // rolled: keep body inside I-cache
    const float* lc = gc + layer * NQ;
    const float* ls = gs + layer * NQ;

    // ---- pass A: own amps a=(t<<5)|j ; rotate q13..q9 (reg bits 0..4). Self-owned slots.
    if (layer > 0) {
#pragma unroll
      for (int i = 0; i < 16; ++i) tile[i] = lds4[baseA + i];
    }
    rot_bit<1>(v, lc[13], ls[13]);
    rot_bit<2>(v, lc[12], ls[12]);
    rot_bit<4>(v, lc[11], ls[11]);
    rot_bit<8>(v, lc[10], ls[10]);
    rot_bit<16>(v, lc[9], ls[9]);
#pragma unroll
    for (int i = 0; i < 16; ++i) lds4[baseA + i] = tile[i];

    // A->B exchange is within a 16-thread group of ONE wave, slots private to the wave:
    // in-order DS pipe makes the data visible without s_barrier. Fence the compiler only.
    __builtin_amdgcn_wave_barrier();

    // ---- pass B: free amp-bits {0,5,6,7,8}; rotate q8..q5 (reg bits 1..4)
#pragma unroll
    for (int jj = 0; jj < 16; ++jj) tile[jj] = lds4[baseB + 17 * jj];
    rot_bit<2>(v, lc[8], ls[8]);
    rot_bit<4>(v, lc[7], ls[7]);
    rot_bit<8>(v, lc[6], ls[6]);
    rot_bit<16>(v, lc[5], ls[5]);
#pragma unroll
    for (int jj = 0; jj < 16; ++jj) lds4[baseB + 17 * jj] = tile[jj];
    __syncthreads();                         // B->C repartition crosses waves

    // ---- pass C: own amps a = t | (j<<9); rotate q4..q0 (reg bits 0..4)
#pragma unroll
    for (int j = 0; j < 16; ++j) v[j] = lds2[baseC + 544 * j];
#pragma unroll
    for (int j = 16; j < 32; ++j) v[j] = lds2[(baseC + 16 * 544) + 544 * (j - 16)];
    rot_bit<1>(v, lc[4], ls[4]);
    rot_bit<2>(v, lc[3], ls[3]);
    rot_bit<4>(v, lc[2], ls[2]);
    rot_bit<8>(v, lc[1], ls[1]);
    rot_bit<16>(v, lc[0], ls[0]);

    if (layer < NL - 1) {
      __syncthreads();                       // WAR: all pass-C reads done
#pragma unroll
      for (int j = 0; j < 32; ++j) *(f2*)(sbase + soff[j]) = v[j];  // CNOT fold
      __syncthreads();                       // RAW for next layer's pass-A read
    }
  }

  // ---- measurement: bit_b(jf(a)) = bit_b(jft) ^ parity(j & m_b)  (GF(2)-linear CNOT)
  {
    float p[32];
#pragma unroll
    for (int j = 0; j < 32; ++j) p[j] = v[j].x * v[j].x + v[j].y * v[j].y;
    // 5-stage Walsh-Hadamard butterfly: p[m] <- sum_j (-1)^popc(j&m) p_j
#pragma unroll
    for (int st = 0; st < 5; ++st) {
      const int h = 1 << st;
#pragma unroll
      for (int j = 0; j < 32; ++j) {
        if (!(j & h)) {
          const float u = p[j], w = p[j | h];
          p[j] = u + w;
          p[j | h] = u - w;
        }
      }
    }
    float av[NQ];
    av[0] = ((jft >> 13) & 1) ? -p[15] : p[15];
    av[1] = ((jft >> 12) & 1) ? -p[24] : p[24];
    av[2] = ((jft >> 11) & 1) ? -p[28] : p[28];
    av[3] = ((jft >> 10) & 1) ? -p[30] : p[30];
#pragma unroll
    for (int q = 4; q < NQ; ++q) av[q] = ((jft >> (13 - q)) & 1) ? -p[31] : p[31];

#pragma unroll
    for (int off = 32; off > 0; off >>= 1)
#pragma unroll
      for (int q = 0; q < NQ; ++q) av[q] += __shfl_down(av[q], off, 64);

    const int wave = t >> 6, lane = t & 63;
    if (lane == 0) {
#pragma unroll
      for (int q = 0; q < NQ; ++q) red[wave][q] = av[q];
    }
    __syncthreads();
    if (t < NQ) {
      float sq = 0.0f;
#pragma unroll
      for (int w = 0; w < 8; ++w) sq += red[w][t];
      out[b * NQ + t] = sq;
    }
  }
}

extern "C" void kernel_launch(void* const* d_in, const int* in_sizes, int n_in,
                              void* d_out, int out_size, void* d_ws, size_t ws_size,
                              hipStream_t stream) {
  const float* x      = (const float*)d_in[0];
  const float* params = (const float*)d_in[1];
  float* out          = (float*)d_out;
  qsim_kernel<<<BATCH, BLK, 0, stream>>>(x, params, out);
}

// Round 6
// 259.479 us; speedup vs baseline: 1.0280x; 1.0280x over previous
//
#include <hip/hip_runtime.h>

#define NQ     14
#define NL     4
#define BATCH  2048
#define DIM    16384
#define BLK    512

using f2 = __attribute__((ext_vector_type(2))) float;

__device__ __forceinline__ f2 swapf2(f2 v) { return __builtin_shufflevector(v, v, 1, 0); }

// RX on register-index bit B of a 32-amp (f2) tile, packed-FP32 form.
template <int B>
__device__ __forceinline__ void rot_bit(f2* v, float c, float s) {
  const f2 C = {c, c};
  const f2 S = {s, -s};
#pragma unroll
  for (int j = 0; j < 32; ++j) {
    if (!(j & B)) {
      const int j1 = j | B;
      const f2 a0 = v[j], a1 = v[j1];
      v[j]  = __builtin_elementwise_fma(C, a0, S * swapf2(a1));
      v[j1] = __builtin_elementwise_fma(C, a1, S * swapf2(a0));
    }
  }
}

// CNOT-ring basis map (linear over GF(2)): jf(k) = (y & 0x1FFF) | ((y0^k13)<<13), y=suffix-xor(k)
__device__ __forceinline__ int cnot_map(int k) {
  int y = k; y ^= y >> 1; y ^= y >> 2; y ^= y >> 4; y ^= y >> 8;
  return (y & 0x1FFF) | (((y ^ (k >> 13)) & 1) << 13);
}
// compile-time images of amp-bits 9..13 under the CNOT map
__host__ __device__ constexpr int G_of(int j) {
  int g = 0;
  if (j & 1)  g ^= 0x23FF;  // M(e9)
  if (j & 2)  g ^= 0x27FF;  // M(e10)
  if (j & 4)  g ^= 0x2FFF;  // M(e11)
  if (j & 8)  g ^= 0x3FFF;  // M(e12)
  if (j & 16) g ^= 0x1FFF;  // M(e13)
  return g;
}

__global__ __launch_bounds__(BLK, 2) void qsim_kernel(const float* __restrict__ x,
                                                      const float* __restrict__ params,
                                                      float* __restrict__ out) {
  // fixed layout: logical chunk c (amps 2c,2c+1) at physical chunk c + (c>>4)
  __shared__ float4 lds4[DIM / 2 + DIM / 32];  // 8704 chunks = 139264 B
  __shared__ float exc[NQ], exs[NQ];
  __shared__ float gc[NL * NQ], gs[NL * NQ];
  __shared__ float red[8][16];
  f2* lds2 = reinterpret_cast<f2*>(lds4);      // f2 slot s -> phys s + 2*(s>>5)

  const int b = blockIdx.x;
  const int t = threadIdx.x;

  if (t < NQ)      { const float xv = x[b * NQ + t]; exc[t] = cosf(0.5f * xv); exs[t] = sinf(0.5f * xv); }
  if (t < NL * NQ) { const float th = 0.5f * params[t]; gc[t] = cosf(th); gs[t] = sinf(th); }
  __syncthreads();

  float4 tile[16];
  f2* v = reinterpret_cast<f2*>(tile);

  // ---- embedding in pass-A ownership: amp a = (t<<5)|j ; a-bit p <-> qubit 13-p
  {
    float pb = 1.0f;
#pragma unroll
    for (int pt = 0; pt < 9; ++pt) pb *= ((t >> pt) & 1) ? exs[8 - pt] : exc[8 - pt];
    const int pct = __popc(t);
#pragma unroll
    for (int j = 0; j < 32; ++j) {
      float f = pb;
#pragma unroll
      for (int bb = 0; bb < 5; ++bb) f *= ((j >> bb) & 1) ? exs[13 - bb] : exc[13 - bb];
      const int pc = (pct + __popc(j)) & 3;
      f2 av;
      av.x = (pc == 0) ? f : ((pc == 2) ? -f : 0.0f);
      av.y = (pc == 1) ? -f : ((pc == 3) ? f : 0.0f);
      v[j] = av;
    }
  }

  const int baseA = 17 * t;                    // phys chunk of c=16t (pass A, self-owned)
  const int baseB = (t & 15) + 272 * (t >> 4); // phys chunk; offsets 17*jj (intra-wave group)
  const int baseC = t + 2 * (t >> 5);          // phys f2 slot; offsets 544*j
  const int jft   = cnot_map(t);

  // CNOT scatter byte-offsets are layer-invariant: precompute once
  int soff[32];
#pragma unroll
  for (int j = 0; j < 32; ++j) {
    const int s = jft ^ G_of(j);
    soff[j] = (s + 2 * (s >> 5)) * 8;          // pad-swizzled f2 slot, in bytes
  }
  char* const sbase = (char*)lds2;

#pragma unroll
  for (int layer = 0; layer < NL; ++layer) {   // fully unrolled (R4): immediate lc/ls offsets
    const float* lc = gc + layer * NQ;
    const float* ls = gs + layer * NQ;

    // ---- pass A: own amps a=(t<<5)|j ; rotate q13..q9 (reg bits 0..4). Self-owned slots.
    if (layer > 0) {
#pragma unroll
      for (int i = 0; i < 16; ++i) tile[i] = lds4[baseA + i];
    }
    rot_bit<1>(v, lc[13], ls[13]);
    rot_bit<2>(v, lc[12], ls[12]);
    rot_bit<4>(v, lc[11], ls[11]);
    rot_bit<8>(v, lc[10], ls[10]);
    rot_bit<16>(v, lc[9], ls[9]);
#pragma unroll
    for (int i = 0; i < 16; ++i) lds4[baseA + i] = tile[i];

    // A->B exchange is wave-private (B sources vary only A-lane bits 0..3):
    // in-order per-wave DS pipe makes data visible; fence the compiler only.
    __builtin_amdgcn_wave_barrier();

    // ---- pass B: free amp-bits {0,5,6,7,8}; rotate q8..q5 (reg bits 1..4)
#pragma unroll
    for (int jj = 0; jj < 16; ++jj) tile[jj] = lds4[baseB + 17 * jj];
    rot_bit<2>(v, lc[8], ls[8]);
    rot_bit<4>(v, lc[7], ls[7]);
    rot_bit<8>(v, lc[6], ls[6]);
    rot_bit<16>(v, lc[5], ls[5]);
#pragma unroll
    for (int jj = 0; jj < 16; ++jj) lds4[baseB + 17 * jj] = tile[jj];
    __syncthreads();                           // B->C repartition crosses waves

    // ---- pass C: own amps a = t | (j<<9); rotate q4..q0 (reg bits 0..4)
#pragma unroll
    for (int j = 0; j < 16; ++j) v[j] = lds2[baseC + 544 * j];
#pragma unroll
    for (int j = 16; j < 32; ++j) v[j] = lds2[(baseC + 16 * 544) + 544 * (j - 16)];
    rot_bit<1>(v, lc[4], ls[4]);
    rot_bit<2>(v, lc[3], ls[3]);
    rot_bit<4>(v, lc[2], ls[2]);
    rot_bit<8>(v, lc[1], ls[1]);
    rot_bit<16>(v, lc[0], ls[0]);

    if (layer < NL - 1) {
      __syncthreads();                         // WAR: all pass-C reads done
#pragma unroll
      for (int j = 0; j < 32; ++j) *(f2*)(sbase + soff[j]) = v[j];  // CNOT fold
      __syncthreads();                         // RAW for next layer's pass-A read
    }
  }

  // ---- measurement: final CNOT folded via GF(2)-linearity.
  // reg-WHT gives per-thread Walsh coeffs; lane signs are Walsh functions of lane
  // (jft bit b = parity(t bits b..8)), so one 6-stage lane butterfly per value
  // yields all masked lane-sums at specific lanes.
  {
    float p[32];
#pragma unroll
    for (int j = 0; j < 32; ++j) p[j] = v[j].x * v[j].x + v[j].y * v[j].y;
#pragma unroll
    for (int st = 0; st < 5; ++st) {
      const int h = 1 << st;
#pragma unroll
      for (int j = 0; j < 32; ++j) {
        if (!(j & h)) {
          const float u = p[j], w = p[j | h];
          p[j] = u + w;
          p[j | h] = u - w;
        }
      }
    }
    float a31 = p[31], a15 = p[15], a24 = p[24], a28 = p[28], a30 = p[30];
    const int lane = t & 63;
#pragma unroll
    for (int m = 0; m < 6; ++m) {
      const int h = 1 << m;
      const bool hi = (lane & h) != 0;
      float u;
      u = __shfl_xor(a31, h, 64); a31 = hi ? (u - a31) : (u + a31);
      u = __shfl_xor(a15, h, 64); a15 = hi ? (u - a15) : (u + a15);
      u = __shfl_xor(a24, h, 64); a24 = u + a24;   // plain sums: only lane 0 used
      u = __shfl_xor(a28, h, 64); a28 = u + a28;
      u = __shfl_xor(a30, h, 64); a30 = u + a30;
    }
    const int w = t >> 6;
    const float sw = (__popc(w) & 1) ? -1.0f : 1.0f;
    if (lane == 0) {
      red[w][1] = a24;                          // q1..q4: sign +1 (jft bits 9..12 = 0)
      red[w][2] = a28;
      red[w][3] = a30;
      red[w][4] = a31;
      red[w][5] = (w & 4) ? -a31 : a31;         // q5: (-1)^t8
      red[w][6] = (((w >> 1) ^ (w >> 2)) & 1) ? -a31 : a31;  // q6: (-1)^(t7^t8)
      red[w][7] = sw * a31;                     // q7: (-1)^(t6^t7^t8)
    } else if (lane == 32) { red[w][8]  = sw * a31; }   // q8:  mask 0x20
    else if (lane == 48)   { red[w][9]  = sw * a31; }   // q9:  mask 0x30
    else if (lane == 56)   { red[w][10] = sw * a31; }   // q10: mask 0x38
    else if (lane == 60)   { red[w][11] = sw * a31; }   // q11: mask 0x3C
    else if (lane == 62)   { red[w][12] = sw * a31; }   // q12: mask 0x3E
    else if (lane == 63)   { red[w][13] = sw * a31;     // q13: mask 0x3F
                             red[w][0]  = sw * a15; }   // q0:  mask 0x3F on p15
    __syncthreads();
    if (t < NQ) {
      float sq = 0.0f;
#pragma unroll
      for (int ww = 0; ww < 8; ++ww) sq += red[ww][t];
      out[b * NQ + t] = sq;
    }
  }
}

extern "C" void kernel_launch(void* const* d_in, const int* in_sizes, int n_in,
                              void* d_out, int out_size, void* d_ws, size_t ws_size,
                              hipStream_t stream) {
  const float* x      = (const float*)d_in[0];
  const float* params = (const float*)d_in[1];
  float* out          = (float*)d_out;
  qsim_kernel<<<BATCH, BLK, 0, stream>>>(x, params, out);
}